// Round 19
// baseline (267.726 us; speedup 1.0000x reference)
//
#include <hip/hip_runtime.h>

#define N_NODES  50000
#define N_EDGES  800000
#define N_GRAPHS 64
#define N_CHUNK  4          // 128 channels / 32
#define ZREP     16         // zsum replicas
#define SCAN_BLOCKS 196     // 196*256 = 50176
#define GATHER_BLOCKS 2048  // per chunk 512 blk x 4 waves x 32 slots = 65536 slots

typedef unsigned short u16x8 __attribute__((ext_vector_type(8)));
typedef short s16x8 __attribute__((ext_vector_type(8)));
typedef float f32x4 __attribute__((ext_vector_type(4)));

__device__ __forceinline__ float bf2f(unsigned short h) {
    return __uint_as_float((unsigned)h << 16);
}
__device__ __forceinline__ unsigned short f2bf(float f) {
    unsigned u = __float_as_uint(f);
    unsigned r = (u + 0x7FFFu + ((u >> 16) & 1u)) >> 16;   // RNE
    return (unsigned short)r;
}
__device__ __forceinline__ unsigned pk2(float a, float b) {
    return (unsigned)f2bf(a) | ((unsigned)f2bf(b) << 16);
}

// ---------------- utility kernels ----------------

__global__ void hist_kernel(const int* __restrict__ ei, int* __restrict__ cnt) {
    const int* dst = ei + N_EDGES;
    for (int e = blockIdx.x * blockDim.x + threadIdx.x; e < N_EDGES; e += gridDim.x * blockDim.x)
        atomicAdd(&cnt[dst[e]], 1);
}

// ---- 3-phase multi-block exclusive scan of cnt[50176] -> rowptr (A also emits dinv) ----
__global__ void scanA_kernel(const int* __restrict__ cnt, int* __restrict__ bsum,
                             float* __restrict__ dinv) {
    __shared__ int wsum[4];
    int t = threadIdx.x;
    int i = blockIdx.x * 256 + t;
    int v = cnt[i];
    if (i < N_NODES) dinv[i] = rsqrtf((float)v + 1.f);   // +1 self-loop
    int s = v;
    #pragma unroll
    for (int off = 1; off < 64; off <<= 1) s += __shfl_xor(s, off);
    if ((t & 63) == 0) wsum[t >> 6] = s;
    __syncthreads();
    if (t == 0) bsum[blockIdx.x] = wsum[0] + wsum[1] + wsum[2] + wsum[3];
}

// scanB also does gcount (batch sorted -> binary search) and zeroes zsumR
__global__ void scanB_kernel(const int* __restrict__ bsum, int* __restrict__ boff,
                             const int* __restrict__ batch, float* __restrict__ cntg,
                             float* __restrict__ zsumR) {
    __shared__ int wsum[4];
    int t = threadIdx.x;
    int lane = t & 63, w = t >> 6;
    int v = (t < SCAN_BLOCKS) ? bsum[t] : 0;
    int s = v;
    #pragma unroll
    for (int off = 1; off < 64; off <<= 1) {
        int u = __shfl_up(s, off);
        if (lane >= off) s += u;
    }
    if (lane == 63) wsum[w] = s;
    __syncthreads();
    int wo = 0;
    for (int j = 0; j < w; ++j) wo += wsum[j];
    if (t < SCAN_BLOCKS) boff[t] = wo + s - v;   // exclusive

    if (t < N_GRAPHS) {
        #pragma unroll
        for (int r = 0; r < ZREP; ++r) zsumR[r * N_GRAPHS + t] = 0.f;
        int g = t;
        int lo = 0, hi = N_NODES;
        while (lo < hi) { int mid = (lo + hi) >> 1; if (batch[mid] < g) lo = mid + 1; else hi = mid; }
        int a = lo;
        lo = 0; hi = N_NODES;
        while (lo < hi) { int mid = (lo + hi) >> 1; if (batch[mid] < g + 1) lo = mid + 1; else hi = mid; }
        cntg[g] = (float)(lo - a);
    }
}

__global__ void scanC_kernel(int* __restrict__ cnt, const int* __restrict__ boff,
                             int* __restrict__ rowptr) {
    __shared__ int wsum[4];
    int t = threadIdx.x;
    int i = blockIdx.x * 256 + t;
    int lane = t & 63, w = t >> 6;
    int v = cnt[i];
    int s = v;
    #pragma unroll
    for (int off = 1; off < 64; off <<= 1) {
        int u = __shfl_up(s, off);
        if (lane >= off) s += u;
    }
    if (lane == 63) wsum[w] = s;
    __syncthreads();
    int wo = 0;
    for (int j = 0; j < w; ++j) wo += wsum[j];
    rowptr[i] = boff[blockIdx.x] + wo + s - v;   // i==N_NODES slot gets total E
    cnt[i] = 0;                                  // reset for fill pass
}

__global__ void fill_kernel(const int* __restrict__ ei, const int* __restrict__ rowptr,
                            int* __restrict__ fill, const float* __restrict__ dinv,
                            int2* __restrict__ csr) {
    const int* src = ei;
    const int* dst = ei + N_EDGES;
    for (int e = blockIdx.x * blockDim.x + threadIdx.x; e < N_EDGES; e += gridDim.x * blockDim.x) {
        int s = src[e], d = dst[e];
        int pos = rowptr[d] + atomicAdd(&fill[d], 1);
        csr[pos] = make_int2(s, __float_as_int(dinv[s] * dinv[d]));
    }
}

// split W into hi/lo bf16, TRANSPOSED to [col][K]
__global__ void prep_w_kernel(const float* __restrict__ W1, const float* __restrict__ W2,
                              unsigned short* __restrict__ w1h, unsigned short* __restrict__ w1l,
                              unsigned short* __restrict__ w2h, unsigned short* __restrict__ w2l) {
    const int n1 = 768 * 128, n2 = 128 * 128;
    for (int i = blockIdx.x * blockDim.x + threadIdx.x; i < n1 + n2; i += gridDim.x * blockDim.x) {
        if (i < n1) {
            int k = i >> 7, c = i & 127;
            float w = W1[i];
            unsigned short hi = f2bf(w);
            unsigned short lo = f2bf(w - bf2f(hi));
            w1h[c * 768 + k] = hi;
            w1l[c * 768 + k] = lo;
        } else {
            int j = i - n1;
            int k = j >> 7, c = j & 127;
            float w = W2[j];
            unsigned short hi = f2bf(w);
            unsigned short lo = f2bf(w - bf2f(hi));
            w2h[c * 128 + k] = hi;
            w2l[c * 128 + k] = lo;
        }
    }
}

// ---------------- MFMA GEMM v3: BM=128 x BN=64 col-split, 782 blocks ----------------
// C[M,128] = A[M,K] @ W[K,128]; W pre-split hi/lo bf16 [col][K] (2 chained mfma
// per fragment => ~fp32-accurate W). Swapped operands; chunk-major ushort4
// stores. Col-split doubles blocks (3/CU -> 12 waves/CU) at constant total W
// staging (per-block W-cols halve); X tiles read 2x (2nd hits L3). Each of 4
// waves owns 16 cols -> acc[8][1]. X and W register-prefetched one K-step.
template<int K, bool BF16A>
__global__ __launch_bounds__(256) void gemm_mfma(const void* __restrict__ Av,
                                                 const unsigned short* __restrict__ Wth,
                                                 const unsigned short* __restrict__ Wtl,
                                                 unsigned short* __restrict__ C, int M) {
    __shared__ unsigned short Xs[128 * 40];
    __shared__ unsigned short Wh[64 * 40];
    __shared__ unsigned short Wl[64 * 40];

    const int tid  = threadIdx.x;
    const int rowblk = blockIdx.x >> 1;
    const int colblk = blockIdx.x & 1;
    const int row0 = rowblk * 128;
    const int col0 = colblk * 64;

    // X staging: trow = tid>>1 (0..127), thalf = (tid&1)*16
    const int trow  = tid >> 1;
    const int thalf = (tid & 1) * 16;
    int grow = row0 + trow;
    if (grow >= M) grow = M - 1;
    const float* xpf = (const float*)Av + (long)grow * K + thalf;
    const unsigned short* xpb = (const unsigned short*)Av + (long)grow * K + thalf;

    // W staging: wc = tid>>2 (0..63 local col), wk8 = (tid&3)*8
    const int wc  = tid >> 2;
    const int wk8 = (tid & 3) * 8;
    const unsigned short* wph = Wth + (long)(col0 + wc) * K + wk8;
    const unsigned short* wpl = Wtl + (long)(col0 + wc) * K + wk8;

    f32x4 acc[8];
    #pragma unroll
    for (int rf = 0; rf < 8; ++rf)
        acc[rf] = (f32x4){0.f, 0.f, 0.f, 0.f};

    // prefetch k0 = 0
    float4 f0, f1, f2, f3;
    uint4 xb0, xb1;
    if constexpr (!BF16A) {
        f0 = *(const float4*)(xpf);
        f1 = *(const float4*)(xpf + 4);
        f2 = *(const float4*)(xpf + 8);
        f3 = *(const float4*)(xpf + 12);
    } else {
        xb0 = *(const uint4*)(xpb);
        xb1 = *(const uint4*)(xpb + 8);
    }
    uint4 whr = *(const uint4*)(wph);
    uint4 wlr = *(const uint4*)(wpl);

    const int l   = tid & 63;
    const int wv  = tid >> 6;
    const int lr  = l & 15;
    const int lk8 = (l >> 4) * 8;

    for (int k0 = 0; k0 < K; k0 += 32) {
        unsigned short* xrow = &Xs[trow * 40 + thalf];
        if constexpr (!BF16A) {
            *(uint4*)(xrow)     = make_uint4(pk2(f0.x, f0.y), pk2(f0.z, f0.w), pk2(f1.x, f1.y), pk2(f1.z, f1.w));
            *(uint4*)(xrow + 8) = make_uint4(pk2(f2.x, f2.y), pk2(f2.z, f2.w), pk2(f3.x, f3.y), pk2(f3.z, f3.w));
        } else {
            *(uint4*)(xrow)     = xb0;
            *(uint4*)(xrow + 8) = xb1;
        }
        *(uint4*)&Wh[wc * 40 + wk8] = whr;
        *(uint4*)&Wl[wc * 40 + wk8] = wlr;
        __syncthreads();

        // prefetch next K-step — overlaps this step's MFMA
        if (k0 + 32 < K) {
            if constexpr (!BF16A) {
                f0 = *(const float4*)(xpf + k0 + 32);
                f1 = *(const float4*)(xpf + k0 + 36);
                f2 = *(const float4*)(xpf + k0 + 40);
                f3 = *(const float4*)(xpf + k0 + 44);
            } else {
                xb0 = *(const uint4*)(xpb + k0 + 32);
                xb1 = *(const uint4*)(xpb + k0 + 40);
            }
            whr = *(const uint4*)(wph + k0 + 32);
            wlr = *(const uint4*)(wpl + k0 + 32);
        }

        s16x8 xb[8], whf, wlf;
        #pragma unroll
        for (int rf = 0; rf < 8; ++rf)
            xb[rf] = *(const s16x8*)&Xs[(rf * 16 + lr) * 40 + lk8];
        whf = *(const s16x8*)&Wh[(wv * 16 + lr) * 40 + lk8];
        wlf = *(const s16x8*)&Wl[(wv * 16 + lr) * 40 + lk8];
        #pragma unroll
        for (int rf = 0; rf < 8; ++rf) {
            acc[rf] = __builtin_amdgcn_mfma_f32_16x16x32_bf16(wlf, xb[rf], acc[rf], 0, 0, 0);
            acc[rf] = __builtin_amdgcn_mfma_f32_16x16x32_bf16(whf, xb[rf], acc[rf], 0, 0, 0);
        }
        __syncthreads();
    }

    const int c4 = (l >> 4) * 4;
    #pragma unroll
    for (int rf = 0; rf < 8; ++rf) {
        int r = row0 + rf * 16 + lr;
        if (r < M) {
            int cb = col0 + wv * 16 + c4;
            ushort4 v;
            v.x = f2bf(acc[rf][0]);
            v.y = f2bf(acc[rf][1]);
            v.z = f2bf(acc[rf][2]);
            v.w = f2bf(acc[rf][3]);
            *(ushort4*)(C + ((long)(cb >> 5) * N_NODES + r) * 32 + (cb & 31)) = v;
        }
    }
}

// ---------------- gather v7: 2 lanes per node, 16 ch each, edge unroll x4 ----------------
// Natural node order; XCD-pinned chunks (blockIdx&7 -> chunk&3). 2048 blocks
// (8/CU -> up to 32 waves/CU) for latency hiding; tail slots exit immediately.
// MODE 0: outbuf (bf16 [node][128]) = relu(agg + bias)
// MODE 1: z = dot(relu(agg+bias), Wl_chunk); zsumR += z (wave-uniform fast path)
template<int MODE>
__global__ __launch_bounds__(256, 6) void gather_all_kernel(
        const unsigned short* __restrict__ xlc, const float* __restrict__ dinv,
        const int* __restrict__ rowptr, const int2* __restrict__ csr,
        const float* __restrict__ bias, unsigned short* __restrict__ outbuf,
        const float* __restrict__ Wl, const int* __restrict__ batch,
        float* __restrict__ zsumR) {
    const int lane = threadIdx.x & 63;
    const int half = lane & 1;            // which 32B half of the 64B row
    const int c0   = half * 16;           // channel offset within chunk (u16 units)

    const int grp   = blockIdx.x & 7;     // ~XCD id (round-robin dispatch)
    const int chunk = grp & 3;
    const unsigned short* xc = xlc + (long)chunk * N_NODES * 32;

    const int cblk = (blockIdx.x >> 3) + (grp >> 2) * 256;  // 0..511 within chunk
    const int wvc  = cblk * 4 + (threadIdx.x >> 6);         // 0..2047 within chunk
    const int slot = wvc * 32 + (lane >> 1);                // 0..65535
    const bool vn  = slot < N_NODES;
    const int node = vn ? slot : N_NODES - 1;

    const int start = rowptr[node];
    const int end   = vn ? rowptr[node + 1] : start;
    const float di  = dinv[node];

    // self half-row (2x16B)
    const u16x8* srow = (const u16x8*)(xc + (long)node * 32 + c0);
    u16x8 s0 = srow[0], s1 = srow[1];

    float acc[16];
    #pragma unroll
    for (int j = 0; j < 16; ++j) acc[j] = 0.f;

    int e = start;
    for (; e + 3 < end; e += 4) {         // divergent; unroll x4 for MLP
        int2 cA = csr[e];
        int2 cB = csr[e + 1];
        int2 cC = csr[e + 2];
        int2 cD = csr[e + 3];
        float wA = __int_as_float(cA.y);
        float wB = __int_as_float(cB.y);
        float wC = __int_as_float(cC.y);
        float wD = __int_as_float(cD.y);
        const u16x8* rA = (const u16x8*)(xc + (long)cA.x * 32 + c0);
        const u16x8* rB = (const u16x8*)(xc + (long)cB.x * 32 + c0);
        const u16x8* rC = (const u16x8*)(xc + (long)cC.x * 32 + c0);
        const u16x8* rD = (const u16x8*)(xc + (long)cD.x * 32 + c0);
        u16x8 a0 = rA[0], a1 = rA[1];
        u16x8 b0 = rB[0], b1 = rB[1];
        u16x8 d0 = rC[0], d1 = rC[1];
        u16x8 e0 = rD[0], e1 = rD[1];
        #pragma unroll
        for (int j = 0; j < 8; ++j) {
            acc[j]     = fmaf(wA, bf2f(a0[j]), acc[j]);
            acc[j + 8] = fmaf(wA, bf2f(a1[j]), acc[j + 8]);
        }
        #pragma unroll
        for (int j = 0; j < 8; ++j) {
            acc[j]     = fmaf(wB, bf2f(b0[j]), acc[j]);
            acc[j + 8] = fmaf(wB, bf2f(b1[j]), acc[j + 8]);
        }
        #pragma unroll
        for (int j = 0; j < 8; ++j) {
            acc[j]     = fmaf(wC, bf2f(d0[j]), acc[j]);
            acc[j + 8] = fmaf(wC, bf2f(d1[j]), acc[j + 8]);
        }
        #pragma unroll
        for (int j = 0; j < 8; ++j) {
            acc[j]     = fmaf(wD, bf2f(e0[j]), acc[j]);
            acc[j + 8] = fmaf(wD, bf2f(e1[j]), acc[j + 8]);
        }
    }
    for (; e < end; ++e) {
        int2 cA = csr[e];
        float wA = __int_as_float(cA.y);
        const u16x8* rA = (const u16x8*)(xc + (long)cA.x * 32 + c0);
        u16x8 a0 = rA[0], a1 = rA[1];
        #pragma unroll
        for (int j = 0; j < 8; ++j) {
            acc[j]     = fmaf(wA, bf2f(a0[j]), acc[j]);
            acc[j + 8] = fmaf(wA, bf2f(a1[j]), acc[j + 8]);
        }
    }

    // self-loop + bias + relu
    const float w2 = di * di;
    const float* bch = bias + chunk * 32 + c0;
    float s[16];
    #pragma unroll
    for (int j = 0; j < 8; ++j) {
        s[j]     = fmaxf(fmaf(w2, bf2f(s0[j]), acc[j])     + bch[j],     0.f);
        s[j + 8] = fmaxf(fmaf(w2, bf2f(s1[j]), acc[j + 8]) + bch[j + 8], 0.f);
    }

    if (MODE == 0) {
        if (vn) {
            unsigned short* op = outbuf + (long)node * 128 + chunk * 32 + c0;
            u16x8 o0, o1;
            #pragma unroll
            for (int j = 0; j < 8; ++j) {
                o0[j] = f2bf(s[j]);
                o1[j] = f2bf(s[j + 8]);
            }
            ((u16x8*)op)[0] = o0;
            ((u16x8*)op)[1] = o1;
        }
    } else {
        const float* wch = Wl + chunk * 32 + c0;
        float z = 0.f;
        #pragma unroll
        for (int j = 0; j < 16; ++j) z = fmaf(s[j], wch[j], z);
        z += __shfl_xor(z, 1);            // combine the two halves -> node total
        if (!vn || half) z = 0.f;
        int b = batch[node];
        int b0v = __shfl(b, 0);
        bool uniform = __all(b == b0v);
        if (uniform) {
            #pragma unroll
            for (int off = 1; off < 64; off <<= 1) z += __shfl_xor(z, off);
            if (lane == 0)
                atomicAdd(&zsumR[(blockIdx.x & (ZREP - 1)) * N_GRAPHS + b0v], z);
        } else if (vn && !half) {
            atomicAdd(&zsumR[((lane >> 1) & (ZREP - 1)) * N_GRAPHS + b], z);
        }
    }
}

__global__ void out_kernel(const float* __restrict__ zsumR, const float* __restrict__ cntg,
                           const float* __restrict__ bl, float* __restrict__ out) {
    int g = threadIdx.x;
    if (g < N_GRAPHS) {
        float z = 0.f;
        #pragma unroll
        for (int r = 0; r < ZREP; ++r) z += zsumR[r * N_GRAPHS + g];
        out[g] = z / fmaxf(cntg[g], 1.f) + bl[0];
    }
}

// ---------------- launch ----------------

extern "C" void kernel_launch(void* const* d_in, const int* in_sizes, int n_in,
                              void* d_out, int out_size, void* d_ws, size_t ws_size,
                              hipStream_t stream) {
    const float* x    = (const float*)d_in[0];
    const int*   ei   = (const int*)d_in[1];
    const int*   batch= (const int*)d_in[2];
    const float* W1   = (const float*)d_in[3];
    const float* b1   = (const float*)d_in[4];
    const float* W2   = (const float*)d_in[5];
    const float* b2   = (const float*)d_in[6];
    const float* Wl   = (const float*)d_in[7];
    const float* bl   = (const float*)d_in[8];
    float* out = (float*)d_out;

    // workspace layout (4B words)
    float* ws      = (float*)d_ws;
    float* dinv    = ws;                          // 50176
    float* zsumR   = ws + 50176;                  // 1024
    float* cntg    = ws + 51200;                  // 64
    int*   cnt_i   = (int*)(ws + 51264);          // 50176
    int*   rowptr  = (int*)(ws + 101440);         // 50176
    int2*  csr     = (int2*)(ws + 151616);        // 800000 int2
    unsigned short* xl16 = (unsigned short*)(ws + 1751616);  // [4][N][32] bf16
    unsigned short* h1   = (unsigned short*)(ws + 1751616 + 3200000);  // [N][128] bf16
    unsigned short* w1h = (unsigned short*)(ws + 11351616);  // 98304 u16
    unsigned short* w1l = w1h + 98304;
    unsigned short* w2h = w1l + 98304;            // 16384 u16
    unsigned short* w2l = w2h + 16384;
    int* bsum = (int*)(w2l + 16384);              // 256
    int* boff = bsum + 256;                       // 256

    hipMemsetAsync(cnt_i, 0, 50176 * sizeof(int), stream);

    hist_kernel<<<1024, 256, 0, stream>>>(ei, cnt_i);
    scanA_kernel<<<SCAN_BLOCKS, 256, 0, stream>>>(cnt_i, bsum, dinv);
    scanB_kernel<<<1, 256, 0, stream>>>(bsum, boff, batch, cntg, zsumR);
    scanC_kernel<<<SCAN_BLOCKS, 256, 0, stream>>>(cnt_i, boff, rowptr);
    fill_kernel<<<1024, 256, 0, stream>>>(ei, rowptr, cnt_i, dinv, csr);
    prep_w_kernel<<<448, 256, 0, stream>>>(W1, W2, w1h, w1l, w2h, w2l);

    // layer 1: xl1 = x@W1 (chunk-major bf16 via MFMA), merged gather -> h1 (bf16)
    gemm_mfma<768, false><<<782, 256, 0, stream>>>(x, w1h, w1l, xl16, N_NODES);
    gather_all_kernel<0><<<GATHER_BLOCKS, 256, 0, stream>>>(
        xl16, dinv, rowptr, csr, b1, h1, nullptr, nullptr, nullptr);

    // layer 2: xl2 = h1@W2 (bf16 in), merged gather + pool
    gemm_mfma<128, true><<<782, 256, 0, stream>>>(h1, w2h, w2l, xl16, N_NODES);
    gather_all_kernel<1><<<GATHER_BLOCKS, 256, 0, stream>>>(
        xl16, dinv, rowptr, csr, b2, nullptr, Wl, batch, zsumR);

    out_kernel<<<1, 64, 0, stream>>>(zsumR, cntg, bl, out);
}

// Round 20
// 236.487 us; speedup vs baseline: 1.1321x; 1.1321x over previous
//
#include <hip/hip_runtime.h>

#define N_NODES  50000
#define N_EDGES  800000
#define N_GRAPHS 64
#define N_CHUNK  4          // 128 channels / 32
#define ZREP     16         // zsum replicas
#define SCAN_BLOCKS 196     // 196*256 = 50176
#define GATHER_BLOCKS 1568  // per chunk 392 blk x 4 waves x 32 nodes = 50176 slots

typedef unsigned short u16x8 __attribute__((ext_vector_type(8)));
typedef short s16x8 __attribute__((ext_vector_type(8)));
typedef float f32x4 __attribute__((ext_vector_type(4)));

__device__ __forceinline__ float bf2f(unsigned short h) {
    return __uint_as_float((unsigned)h << 16);
}
__device__ __forceinline__ unsigned short f2bf(float f) {
    unsigned u = __float_as_uint(f);
    unsigned r = (u + 0x7FFFu + ((u >> 16) & 1u)) >> 16;   // RNE
    return (unsigned short)r;
}
__device__ __forceinline__ unsigned pk2(float a, float b) {
    return (unsigned)f2bf(a) | ((unsigned)f2bf(b) << 16);
}

// ---------------- utility kernels ----------------

__global__ void hist_kernel(const int* __restrict__ ei, int* __restrict__ cnt) {
    const int* dst = ei + N_EDGES;
    for (int e = blockIdx.x * blockDim.x + threadIdx.x; e < N_EDGES; e += gridDim.x * blockDim.x)
        atomicAdd(&cnt[dst[e]], 1);
}

// ---- 3-phase multi-block exclusive scan of cnt[50176] -> rowptr (A also emits dinv) ----
__global__ void scanA_kernel(const int* __restrict__ cnt, int* __restrict__ bsum,
                             float* __restrict__ dinv) {
    __shared__ int wsum[4];
    int t = threadIdx.x;
    int i = blockIdx.x * 256 + t;
    int v = cnt[i];
    if (i < N_NODES) dinv[i] = rsqrtf((float)v + 1.f);   // +1 self-loop
    int s = v;
    #pragma unroll
    for (int off = 1; off < 64; off <<= 1) s += __shfl_xor(s, off);
    if ((t & 63) == 0) wsum[t >> 6] = s;
    __syncthreads();
    if (t == 0) bsum[blockIdx.x] = wsum[0] + wsum[1] + wsum[2] + wsum[3];
}

// scanB also does gcount (batch sorted -> binary search) and zeroes zsumR
__global__ void scanB_kernel(const int* __restrict__ bsum, int* __restrict__ boff,
                             const int* __restrict__ batch, float* __restrict__ cntg,
                             float* __restrict__ zsumR) {
    __shared__ int wsum[4];
    int t = threadIdx.x;
    int lane = t & 63, w = t >> 6;
    int v = (t < SCAN_BLOCKS) ? bsum[t] : 0;
    int s = v;
    #pragma unroll
    for (int off = 1; off < 64; off <<= 1) {
        int u = __shfl_up(s, off);
        if (lane >= off) s += u;
    }
    if (lane == 63) wsum[w] = s;
    __syncthreads();
    int wo = 0;
    for (int j = 0; j < w; ++j) wo += wsum[j];
    if (t < SCAN_BLOCKS) boff[t] = wo + s - v;   // exclusive

    if (t < N_GRAPHS) {
        #pragma unroll
        for (int r = 0; r < ZREP; ++r) zsumR[r * N_GRAPHS + t] = 0.f;
        int g = t;
        int lo = 0, hi = N_NODES;
        while (lo < hi) { int mid = (lo + hi) >> 1; if (batch[mid] < g) lo = mid + 1; else hi = mid; }
        int a = lo;
        lo = 0; hi = N_NODES;
        while (lo < hi) { int mid = (lo + hi) >> 1; if (batch[mid] < g + 1) lo = mid + 1; else hi = mid; }
        cntg[g] = (float)(lo - a);
    }
}

__global__ void scanC_kernel(int* __restrict__ cnt, const int* __restrict__ boff,
                             int* __restrict__ rowptr) {
    __shared__ int wsum[4];
    int t = threadIdx.x;
    int i = blockIdx.x * 256 + t;
    int lane = t & 63, w = t >> 6;
    int v = cnt[i];
    int s = v;
    #pragma unroll
    for (int off = 1; off < 64; off <<= 1) {
        int u = __shfl_up(s, off);
        if (lane >= off) s += u;
    }
    if (lane == 63) wsum[w] = s;
    __syncthreads();
    int wo = 0;
    for (int j = 0; j < w; ++j) wo += wsum[j];
    rowptr[i] = boff[blockIdx.x] + wo + s - v;   // i==N_NODES slot gets total E
    cnt[i] = 0;                                  // reset for fill pass
}

__global__ void fill_kernel(const int* __restrict__ ei, const int* __restrict__ rowptr,
                            int* __restrict__ fill, const float* __restrict__ dinv,
                            int2* __restrict__ csr) {
    const int* src = ei;
    const int* dst = ei + N_EDGES;
    for (int e = blockIdx.x * blockDim.x + threadIdx.x; e < N_EDGES; e += gridDim.x * blockDim.x) {
        int s = src[e], d = dst[e];
        int pos = rowptr[d] + atomicAdd(&fill[d], 1);
        csr[pos] = make_int2(s, __float_as_int(dinv[s] * dinv[d]));
    }
}

// split W into hi/lo bf16, TRANSPOSED to [col][K]
__global__ void prep_w_kernel(const float* __restrict__ W1, const float* __restrict__ W2,
                              unsigned short* __restrict__ w1h, unsigned short* __restrict__ w1l,
                              unsigned short* __restrict__ w2h, unsigned short* __restrict__ w2l) {
    const int n1 = 768 * 128, n2 = 128 * 128;
    for (int i = blockIdx.x * blockDim.x + threadIdx.x; i < n1 + n2; i += gridDim.x * blockDim.x) {
        if (i < n1) {
            int k = i >> 7, c = i & 127;
            float w = W1[i];
            unsigned short hi = f2bf(w);
            unsigned short lo = f2bf(w - bf2f(hi));
            w1h[c * 768 + k] = hi;
            w1l[c * 768 + k] = lo;
        } else {
            int j = i - n1;
            int k = j >> 7, c = j & 127;
            float w = W2[j];
            unsigned short hi = f2bf(w);
            unsigned short lo = f2bf(w - bf2f(hi));
            w2h[c * 128 + k] = hi;
            w2l[c * 128 + k] = lo;
        }
    }
}

// ---------------- MFMA GEMM (BM=128, X AND W register-prefetched) ----------------
// C[M,128] = A[M,K] @ W[K,128]; W pre-split hi/lo bf16 [col][K] (2 chained mfma
// per fragment => ~fp32-accurate W). Swapped operands (A-op = W^T, B-op = x);
// chunk-major ushort4 stores. Tile 128x128, BK=32, 4 waves; LDS rows padded
// to 40 u16. NOTE: per-K-iteration overhead (staging + 2 barriers) is constant
// while splits cut MFMA/iter -> BM=64 (R17) and BN=64 (R19) both regressed 2x.
// This BM128/BK32 config is the measured optimum of this loop structure.
template<int K, bool BF16A>
__global__ __launch_bounds__(256) void gemm_mfma(const void* __restrict__ Av,
                                                 const unsigned short* __restrict__ Wth,
                                                 const unsigned short* __restrict__ Wtl,
                                                 unsigned short* __restrict__ C, int M) {
    __shared__ unsigned short Xs[128 * 40];
    __shared__ unsigned short Wh[128 * 40];
    __shared__ unsigned short Wl[128 * 40];

    const int tid  = threadIdx.x;
    const int row0 = blockIdx.x * 128;
    const int trow  = tid >> 1;          // 0..127 (X row / W col staged by this thread)
    const int thalf = (tid & 1) * 16;    // element offset 0 or 16

    int grow = row0 + trow;
    if (grow >= M) grow = M - 1;
    const float* xpf = (const float*)Av + (long)grow * K + thalf;
    const unsigned short* xpb = (const unsigned short*)Av + (long)grow * K + thalf;
    const unsigned short* wph = Wth + (long)trow * K + thalf;
    const unsigned short* wpl = Wtl + (long)trow * K + thalf;

    f32x4 acc[8][2];
    #pragma unroll
    for (int rf = 0; rf < 8; ++rf)
        #pragma unroll
        for (int cf = 0; cf < 2; ++cf)
            acc[rf][cf] = (f32x4){0.f, 0.f, 0.f, 0.f};

    // prefetch k0 = 0: X slice and W slice into registers
    float4 f0, f1, f2, f3;
    uint4 xb0, xb1;
    if constexpr (!BF16A) {
        f0 = *(const float4*)(xpf);
        f1 = *(const float4*)(xpf + 4);
        f2 = *(const float4*)(xpf + 8);
        f3 = *(const float4*)(xpf + 12);
    } else {
        xb0 = *(const uint4*)(xpb);
        xb1 = *(const uint4*)(xpb + 8);
    }
    uint4 wh0 = ((const uint4*)(wph))[0];
    uint4 wh1 = ((const uint4*)(wph))[1];
    uint4 wl0 = ((const uint4*)(wpl))[0];
    uint4 wl1 = ((const uint4*)(wpl))[1];

    const int l   = tid & 63;
    const int wv  = tid >> 6;
    const int lr  = l & 15;
    const int lk8 = (l >> 4) * 8;

    for (int k0 = 0; k0 < K; k0 += 32) {
        // write staged registers to LDS
        unsigned short* xrow = &Xs[trow * 40 + thalf];
        if constexpr (!BF16A) {
            *(uint4*)(xrow)     = make_uint4(pk2(f0.x, f0.y), pk2(f0.z, f0.w), pk2(f1.x, f1.y), pk2(f1.z, f1.w));
            *(uint4*)(xrow + 8) = make_uint4(pk2(f2.x, f2.y), pk2(f2.z, f2.w), pk2(f3.x, f3.y), pk2(f3.z, f3.w));
        } else {
            *(uint4*)(xrow)     = xb0;
            *(uint4*)(xrow + 8) = xb1;
        }
        *(uint4*)&Wh[trow * 40 + thalf]     = wh0;
        *(uint4*)&Wh[trow * 40 + thalf + 8] = wh1;
        *(uint4*)&Wl[trow * 40 + thalf]     = wl0;
        *(uint4*)&Wl[trow * 40 + thalf + 8] = wl1;
        __syncthreads();

        // prefetch next K-step (X and W) — overlaps with this step's MFMA
        if (k0 + 32 < K) {
            if constexpr (!BF16A) {
                f0 = *(const float4*)(xpf + k0 + 32);
                f1 = *(const float4*)(xpf + k0 + 36);
                f2 = *(const float4*)(xpf + k0 + 40);
                f3 = *(const float4*)(xpf + k0 + 44);
            } else {
                xb0 = *(const uint4*)(xpb + k0 + 32);
                xb1 = *(const uint4*)(xpb + k0 + 40);
            }
            wh0 = ((const uint4*)(wph + k0 + 32))[0];
            wh1 = ((const uint4*)(wph + k0 + 32))[1];
            wl0 = ((const uint4*)(wpl + k0 + 32))[0];
            wl1 = ((const uint4*)(wpl + k0 + 32))[1];
        }

        s16x8 xb[8], whf[2], wlf[2];
        #pragma unroll
        for (int rf = 0; rf < 8; ++rf)
            xb[rf] = *(const s16x8*)&Xs[(rf * 16 + lr) * 40 + lk8];
        #pragma unroll
        for (int cf = 0; cf < 2; ++cf) {
            whf[cf] = *(const s16x8*)&Wh[(wv * 32 + cf * 16 + lr) * 40 + lk8];
            wlf[cf] = *(const s16x8*)&Wl[(wv * 32 + cf * 16 + lr) * 40 + lk8];
        }
        #pragma unroll
        for (int rf = 0; rf < 8; ++rf)
            #pragma unroll
            for (int cf = 0; cf < 2; ++cf) {
                acc[rf][cf] = __builtin_amdgcn_mfma_f32_16x16x32_bf16(wlf[cf], xb[rf], acc[rf][cf], 0, 0, 0);
                acc[rf][cf] = __builtin_amdgcn_mfma_f32_16x16x32_bf16(whf[cf], xb[rf], acc[rf][cf], 0, 0, 0);
            }
        __syncthreads();
    }

    const int c4 = (l >> 4) * 4;
    #pragma unroll
    for (int rf = 0; rf < 8; ++rf) {
        int r = row0 + rf * 16 + lr;
        if (r < M) {
            #pragma unroll
            for (int cf = 0; cf < 2; ++cf) {
                int cb = wv * 32 + cf * 16 + c4;
                ushort4 v;
                v.x = f2bf(acc[rf][cf][0]);
                v.y = f2bf(acc[rf][cf][1]);
                v.z = f2bf(acc[rf][cf][2]);
                v.w = f2bf(acc[rf][cf][3]);
                *(ushort4*)(C + ((long)(cb >> 5) * N_NODES + r) * 32 + (cb & 31)) = v;
            }
        }
    }
}

// ---------------- gather v6: 2 lanes per node, 16 ch each, edge unroll x4 ----------------
// Natural node order; XCD-pinned chunks (blockIdx&7 -> chunk&3). Lane pair
// (2i,2i+1) owns node-slot i; each lane walks the edge list over ITS 16
// channels with 4 edges in flight (8 row-half loads).
// MODE 0: outbuf (bf16 [node][128]) = relu(agg + bias)
// MODE 1: z = dot(relu(agg+bias), Wl_chunk); zsumR += z (wave-uniform fast path)
template<int MODE>
__global__ __launch_bounds__(256, 6) void gather_all_kernel(
        const unsigned short* __restrict__ xlc, const float* __restrict__ dinv,
        const int* __restrict__ rowptr, const int2* __restrict__ csr,
        const float* __restrict__ bias, unsigned short* __restrict__ outbuf,
        const float* __restrict__ Wl, const int* __restrict__ batch,
        float* __restrict__ zsumR) {
    const int lane = threadIdx.x & 63;
    const int half = lane & 1;            // which 32B half of the 64B row
    const int c0   = half * 16;           // channel offset within chunk (u16 units)

    const int grp   = blockIdx.x & 7;     // ~XCD id (round-robin dispatch)
    const int chunk = grp & 3;
    const unsigned short* xc = xlc + (long)chunk * N_NODES * 32;

    const int cblk = (blockIdx.x >> 3) + (grp >> 2) * 196;  // 0..391 within chunk
    const int wvc  = cblk * 4 + (threadIdx.x >> 6);         // 0..1567 within chunk
    const int slot = wvc * 32 + (lane >> 1);
    const bool vn  = slot < N_NODES;
    const int node = vn ? slot : N_NODES - 1;

    const int start = rowptr[node];
    const int end   = vn ? rowptr[node + 1] : start;
    const float di  = dinv[node];

    // self half-row (2x16B)
    const u16x8* srow = (const u16x8*)(xc + (long)node * 32 + c0);
    u16x8 s0 = srow[0], s1 = srow[1];

    float acc[16];
    #pragma unroll
    for (int j = 0; j < 16; ++j) acc[j] = 0.f;

    int e = start;
    for (; e + 3 < end; e += 4) {         // divergent; unroll x4 for MLP
        int2 cA = csr[e];
        int2 cB = csr[e + 1];
        int2 cC = csr[e + 2];
        int2 cD = csr[e + 3];
        float wA = __int_as_float(cA.y);
        float wB = __int_as_float(cB.y);
        float wC = __int_as_float(cC.y);
        float wD = __int_as_float(cD.y);
        const u16x8* rA = (const u16x8*)(xc + (long)cA.x * 32 + c0);
        const u16x8* rB = (const u16x8*)(xc + (long)cB.x * 32 + c0);
        const u16x8* rC = (const u16x8*)(xc + (long)cC.x * 32 + c0);
        const u16x8* rD = (const u16x8*)(xc + (long)cD.x * 32 + c0);
        u16x8 a0 = rA[0], a1 = rA[1];
        u16x8 b0 = rB[0], b1 = rB[1];
        u16x8 d0 = rC[0], d1 = rC[1];
        u16x8 e0 = rD[0], e1 = rD[1];
        #pragma unroll
        for (int j = 0; j < 8; ++j) {
            acc[j]     = fmaf(wA, bf2f(a0[j]), acc[j]);
            acc[j + 8] = fmaf(wA, bf2f(a1[j]), acc[j + 8]);
        }
        #pragma unroll
        for (int j = 0; j < 8; ++j) {
            acc[j]     = fmaf(wB, bf2f(b0[j]), acc[j]);
            acc[j + 8] = fmaf(wB, bf2f(b1[j]), acc[j + 8]);
        }
        #pragma unroll
        for (int j = 0; j < 8; ++j) {
            acc[j]     = fmaf(wC, bf2f(d0[j]), acc[j]);
            acc[j + 8] = fmaf(wC, bf2f(d1[j]), acc[j + 8]);
        }
        #pragma unroll
        for (int j = 0; j < 8; ++j) {
            acc[j]     = fmaf(wD, bf2f(e0[j]), acc[j]);
            acc[j + 8] = fmaf(wD, bf2f(e1[j]), acc[j + 8]);
        }
    }
    for (; e < end; ++e) {
        int2 cA = csr[e];
        float wA = __int_as_float(cA.y);
        const u16x8* rA = (const u16x8*)(xc + (long)cA.x * 32 + c0);
        u16x8 a0 = rA[0], a1 = rA[1];
        #pragma unroll
        for (int j = 0; j < 8; ++j) {
            acc[j]     = fmaf(wA, bf2f(a0[j]), acc[j]);
            acc[j + 8] = fmaf(wA, bf2f(a1[j]), acc[j + 8]);
        }
    }

    // self-loop + bias + relu
    const float w2 = di * di;
    const float* bch = bias + chunk * 32 + c0;
    float s[16];
    #pragma unroll
    for (int j = 0; j < 8; ++j) {
        s[j]     = fmaxf(fmaf(w2, bf2f(s0[j]), acc[j])     + bch[j],     0.f);
        s[j + 8] = fmaxf(fmaf(w2, bf2f(s1[j]), acc[j + 8]) + bch[j + 8], 0.f);
    }

    if (MODE == 0) {
        if (vn) {
            unsigned short* op = outbuf + (long)node * 128 + chunk * 32 + c0;
            u16x8 o0, o1;
            #pragma unroll
            for (int j = 0; j < 8; ++j) {
                o0[j] = f2bf(s[j]);
                o1[j] = f2bf(s[j + 8]);
            }
            ((u16x8*)op)[0] = o0;
            ((u16x8*)op)[1] = o1;
        }
    } else {
        const float* wch = Wl + chunk * 32 + c0;
        float z = 0.f;
        #pragma unroll
        for (int j = 0; j < 16; ++j) z = fmaf(s[j], wch[j], z);
        z += __shfl_xor(z, 1);            // combine the two halves -> node total
        if (!vn || half) z = 0.f;
        int b = batch[node];
        int b0v = __shfl(b, 0);
        bool uniform = __all(b == b0v);
        if (uniform) {
            #pragma unroll
            for (int off = 1; off < 64; off <<= 1) z += __shfl_xor(z, off);
            if (lane == 0)
                atomicAdd(&zsumR[(blockIdx.x & (ZREP - 1)) * N_GRAPHS + b0v], z);
        } else if (vn && !half) {
            atomicAdd(&zsumR[((lane >> 1) & (ZREP - 1)) * N_GRAPHS + b], z);
        }
    }
}

__global__ void out_kernel(const float* __restrict__ zsumR, const float* __restrict__ cntg,
                           const float* __restrict__ bl, float* __restrict__ out) {
    int g = threadIdx.x;
    if (g < N_GRAPHS) {
        float z = 0.f;
        #pragma unroll
        for (int r = 0; r < ZREP; ++r) z += zsumR[r * N_GRAPHS + g];
        out[g] = z / fmaxf(cntg[g], 1.f) + bl[0];
    }
}

// ---------------- launch ----------------

extern "C" void kernel_launch(void* const* d_in, const int* in_sizes, int n_in,
                              void* d_out, int out_size, void* d_ws, size_t ws_size,
                              hipStream_t stream) {
    const float* x    = (const float*)d_in[0];
    const int*   ei   = (const int*)d_in[1];
    const int*   batch= (const int*)d_in[2];
    const float* W1   = (const float*)d_in[3];
    const float* b1   = (const float*)d_in[4];
    const float* W2   = (const float*)d_in[5];
    const float* b2   = (const float*)d_in[6];
    const float* Wl   = (const float*)d_in[7];
    const float* bl   = (const float*)d_in[8];
    float* out = (float*)d_out;

    // workspace layout (4B words)
    float* ws      = (float*)d_ws;
    float* dinv    = ws;                          // 50176
    float* zsumR   = ws + 50176;                  // 1024
    float* cntg    = ws + 51200;                  // 64
    int*   cnt_i   = (int*)(ws + 51264);          // 50176
    int*   rowptr  = (int*)(ws + 101440);         // 50176
    int2*  csr     = (int2*)(ws + 151616);        // 800000 int2
    unsigned short* xl16 = (unsigned short*)(ws + 1751616);  // [4][N][32] bf16
    unsigned short* h1   = (unsigned short*)(ws + 1751616 + 3200000);  // [N][128] bf16
    unsigned short* w1h = (unsigned short*)(ws + 11351616);  // 98304 u16
    unsigned short* w1l = w1h + 98304;
    unsigned short* w2h = w1l + 98304;            // 16384 u16
    unsigned short* w2l = w2h + 16384;
    int* bsum = (int*)(w2l + 16384);              // 256
    int* boff = bsum + 256;                       // 256

    hipMemsetAsync(cnt_i, 0, 50176 * sizeof(int), stream);

    hist_kernel<<<1024, 256, 0, stream>>>(ei, cnt_i);
    scanA_kernel<<<SCAN_BLOCKS, 256, 0, stream>>>(cnt_i, bsum, dinv);
    scanB_kernel<<<1, 256, 0, stream>>>(bsum, boff, batch, cntg, zsumR);
    scanC_kernel<<<SCAN_BLOCKS, 256, 0, stream>>>(cnt_i, boff, rowptr);
    fill_kernel<<<1024, 256, 0, stream>>>(ei, rowptr, cnt_i, dinv, csr);
    prep_w_kernel<<<448, 256, 0, stream>>>(W1, W2, w1h, w1l, w2h, w2l);

    // layer 1: xl1 = x@W1 (chunk-major bf16 via MFMA), merged gather -> h1 (bf16)
    gemm_mfma<768, false><<<391, 256, 0, stream>>>(x, w1h, w1l, xl16, N_NODES);
    gather_all_kernel<0><<<GATHER_BLOCKS, 256, 0, stream>>>(
        xl16, dinv, rowptr, csr, b1, h1, nullptr, nullptr, nullptr);

    // layer 2: xl2 = h1@W2 (bf16 in), merged gather + pool
    gemm_mfma<128, true><<<391, 256, 0, stream>>>(h1, w2h, w2l, xl16, N_NODES);
    gather_all_kernel<1><<<GATHER_BLOCKS, 256, 0, stream>>>(
        xl16, dinv, rowptr, csr, b2, nullptr, Wl, batch, zsumR);

    out_kernel<<<1, 64, 0, stream>>>(zsumR, cntg, bl, out);
}